// Round 1
// baseline (144.717 us; speedup 1.0000x reference)
//
#include <hip/hip_runtime.h>
#include <math.h>

#define NS 4
#define SINKHORN_ITERS 10
#define TAU 0.05f

// T*D/4 in float4 units: 4096*2048/4 = 2^21
#define PLANE4 2097152
#define PLANE4_SHIFT 21

// ---------------------------------------------------------------------------
// Kernel 1: compute M[4][4] = H_res^T + H_post (outer) H_pre  into d_ws.
// Tiny (4x4, 10 sinkhorn iters) -> one thread.
// ---------------------------------------------------------------------------
__global__ void hc_coef_kernel(const float* __restrict__ Hres_logits,
                               const float* __restrict__ Hpre_logits,
                               const float* __restrict__ Hpost_logits,
                               float* __restrict__ M) {
    if (threadIdx.x != 0 || blockIdx.x != 0) return;

    float Z[NS][NS], u[NS], v[NS];
    for (int i = 0; i < NS; ++i)
        for (int j = 0; j < NS; ++j)
            Z[i][j] = Hres_logits[i * NS + j] / TAU;

    const float logm = -logf((float)NS);
    for (int i = 0; i < NS; ++i) { u[i] = 0.f; v[i] = 0.f; }

    for (int it = 0; it < SINKHORN_ITERS; ++it) {
        // u = logm - logsumexp_j(Z[i][j] + v[j])
        for (int i = 0; i < NS; ++i) {
            float mx = -INFINITY;
            for (int j = 0; j < NS; ++j) mx = fmaxf(mx, Z[i][j] + v[j]);
            float s = 0.f;
            for (int j = 0; j < NS; ++j) s += expf(Z[i][j] + v[j] - mx);
            u[i] = logm - (mx + logf(s));
        }
        // v = logm - logsumexp_i(Z[i][j] + u[i])
        for (int j = 0; j < NS; ++j) {
            float mx = -INFINITY;
            for (int i = 0; i < NS; ++i) mx = fmaxf(mx, Z[i][j] + u[i]);
            float s = 0.f;
            for (int i = 0; i < NS; ++i) s += expf(Z[i][j] + u[i] - mx);
            v[j] = logm - (mx + logf(s));
        }
    }

    float Hres[NS][NS];
    for (int i = 0; i < NS; ++i)
        for (int j = 0; j < NS; ++j)
            Hres[i][j] = expf(Z[i][j] + u[i] + v[j]) * (float)NS;

    // softmax(H_pre_logits)
    float hp[NS], mx = -INFINITY, s = 0.f;
    for (int i = 0; i < NS; ++i) mx = fmaxf(mx, Hpre_logits[i]);
    for (int i = 0; i < NS; ++i) { hp[i] = expf(Hpre_logits[i] - mx); s += hp[i]; }
    for (int i = 0; i < NS; ++i) hp[i] /= s;

    // softmax(H_post_logits)
    float ho[NS];
    mx = -INFINITY; s = 0.f;
    for (int i = 0; i < NS; ++i) mx = fmaxf(mx, Hpost_logits[i]);
    for (int i = 0; i < NS; ++i) { ho[i] = expf(Hpost_logits[i] - mx); s += ho[i]; }
    for (int i = 0; i < NS; ++i) ho[i] /= s;

    // out[(b,so),l,d] = sum_si (Hres[si][so] + ho[so]*hp[si]) * in[(b,si),l,d]
    for (int so = 0; so < NS; ++so)
        for (int si = 0; si < NS; ++si)
            M[so * NS + si] = Hres[si][so] + ho[so] * hp[si];
}

// ---------------------------------------------------------------------------
// Kernel 2: memory-bound 4-stream mix. One thread = one (b, l*D+d) position
// (float4-vectorized): 4 coalesced loads, 16 FMAs/component, 4 stores.
// ---------------------------------------------------------------------------
__global__ __launch_bounds__(256) void hc_mix_kernel(
        const float4* __restrict__ in,
        const float* __restrict__ Mg,
        float4* __restrict__ out,
        int npos4) {
    float m[16];
#pragma unroll
    for (int k = 0; k < 16; ++k) m[k] = Mg[k];

    const int stride = gridDim.x * blockDim.x;
    for (int p = blockIdx.x * blockDim.x + threadIdx.x; p < npos4; p += stride) {
        const int b = p >> PLANE4_SHIFT;          // batch index (0..1)
        const int q = p & (PLANE4 - 1);           // position within (t,d) plane
        const long base = ((long)(b * NS) << PLANE4_SHIFT) + q;

        const float4 v0 = in[base];
        const float4 v1 = in[base + PLANE4];
        const float4 v2 = in[base + 2 * PLANE4];
        const float4 v3 = in[base + 3 * PLANE4];

#pragma unroll
        for (int o = 0; o < NS; ++o) {
            float4 r;
            r.x = m[o*4+0]*v0.x + m[o*4+1]*v1.x + m[o*4+2]*v2.x + m[o*4+3]*v3.x;
            r.y = m[o*4+0]*v0.y + m[o*4+1]*v1.y + m[o*4+2]*v2.y + m[o*4+3]*v3.y;
            r.z = m[o*4+0]*v0.z + m[o*4+1]*v1.z + m[o*4+2]*v2.z + m[o*4+3]*v3.z;
            r.w = m[o*4+0]*v0.w + m[o*4+1]*v1.w + m[o*4+2]*v2.w + m[o*4+3]*v3.w;
            out[base + (long)o * PLANE4] = r;
        }
    }
}

extern "C" void kernel_launch(void* const* d_in, const int* in_sizes, int n_in,
                              void* d_out, int out_size, void* d_ws, size_t ws_size,
                              hipStream_t stream) {
    const float* residuals   = (const float*)d_in[0];  // (B*S, T, D) = (8,4096,2048) f32
    const float* Hres_logits = (const float*)d_in[1];  // (4,4)
    const float* Hpre_logits = (const float*)d_in[2];  // (4,)
    const float* Hpost_logits= (const float*)d_in[3];  // (4,)
    float* out = (float*)d_out;
    float* M   = (float*)d_ws;                         // 16 floats

    hc_coef_kernel<<<1, 64, 0, stream>>>(Hres_logits, Hpre_logits, Hpost_logits, M);

    const int npos4 = out_size / (NS * 4);             // B*T*D/4 = 4194304
    hc_mix_kernel<<<2048, 256, 0, stream>>>(
        (const float4*)residuals, M, (float4*)out, npos4);
}

// Round 3
// 128.624 us; speedup vs baseline: 1.1251x; 1.1251x over previous
//
#include <hip/hip_runtime.h>
#include <math.h>

#define NS 4
#define SINKHORN_ITERS 10
#define TAU 0.05f

// T*D/4 in float4 units: 4096*2048/4 = 2^21
#define PLANE4 2097152
#define PLANE4_SHIFT 21

typedef float f32x4 __attribute__((ext_vector_type(4)));

// ---------------------------------------------------------------------------
// Kernel 1: compute M[4][4] = H_res^T + H_post (outer) H_pre  into d_ws.
// ---------------------------------------------------------------------------
__global__ void hc_coef_kernel(const float* __restrict__ Hres_logits,
                               const float* __restrict__ Hpre_logits,
                               const float* __restrict__ Hpost_logits,
                               float* __restrict__ M) {
    if (threadIdx.x != 0 || blockIdx.x != 0) return;

    float Z[NS][NS], u[NS], v[NS];
    for (int i = 0; i < NS; ++i)
        for (int j = 0; j < NS; ++j)
            Z[i][j] = Hres_logits[i * NS + j] / TAU;

    const float logm = -logf((float)NS);
    for (int i = 0; i < NS; ++i) { u[i] = 0.f; v[i] = 0.f; }

    for (int it = 0; it < SINKHORN_ITERS; ++it) {
        for (int i = 0; i < NS; ++i) {
            float mx = -INFINITY;
            for (int j = 0; j < NS; ++j) mx = fmaxf(mx, Z[i][j] + v[j]);
            float s = 0.f;
            for (int j = 0; j < NS; ++j) s += expf(Z[i][j] + v[j] - mx);
            u[i] = logm - (mx + logf(s));
        }
        for (int j = 0; j < NS; ++j) {
            float mx = -INFINITY;
            for (int i = 0; i < NS; ++i) mx = fmaxf(mx, Z[i][j] + u[i]);
            float s = 0.f;
            for (int i = 0; i < NS; ++i) s += expf(Z[i][j] + u[i] - mx);
            v[j] = logm - (mx + logf(s));
        }
    }

    float Hres[NS][NS];
    for (int i = 0; i < NS; ++i)
        for (int j = 0; j < NS; ++j)
            Hres[i][j] = expf(Z[i][j] + u[i] + v[j]) * (float)NS;

    float hp[NS], mx = -INFINITY, s = 0.f;
    for (int i = 0; i < NS; ++i) mx = fmaxf(mx, Hpre_logits[i]);
    for (int i = 0; i < NS; ++i) { hp[i] = expf(Hpre_logits[i] - mx); s += hp[i]; }
    for (int i = 0; i < NS; ++i) hp[i] /= s;

    float ho[NS];
    mx = -INFINITY; s = 0.f;
    for (int i = 0; i < NS; ++i) mx = fmaxf(mx, Hpost_logits[i]);
    for (int i = 0; i < NS; ++i) { ho[i] = expf(Hpost_logits[i] - mx); s += ho[i]; }
    for (int i = 0; i < NS; ++i) ho[i] /= s;

    for (int so = 0; so < NS; ++so)
        for (int si = 0; si < NS; ++si)
            M[so * NS + si] = Hres[si][so] + ho[so] * hp[si];
}

// ---------------------------------------------------------------------------
// Kernel 2: 4-stream mix, unroll x2 for MLP (8 loads in flight / wave),
// nontemporal streaming loads+stores.
// ---------------------------------------------------------------------------
__global__ __launch_bounds__(256) void hc_mix_kernel(
        const f32x4* __restrict__ in,
        const float* __restrict__ Mg,
        f32x4* __restrict__ out,
        int npos4) {
    float m[16];
#pragma unroll
    for (int k = 0; k < 16; ++k) m[k] = Mg[k];

    const int stride = gridDim.x * blockDim.x;
    int p = blockIdx.x * blockDim.x + threadIdx.x;

    for (; p < npos4; p += 2 * stride) {
        const int p2 = p + stride;

        // --- position A: issue 4 loads ---
        const int bA = p >> PLANE4_SHIFT;
        const long baseA = ((long)(bA * NS) << PLANE4_SHIFT) + (p & (PLANE4 - 1));
        const f32x4 a0 = __builtin_nontemporal_load(&in[baseA]);
        const f32x4 a1 = __builtin_nontemporal_load(&in[baseA + PLANE4]);
        const f32x4 a2 = __builtin_nontemporal_load(&in[baseA + 2 * PLANE4]);
        const f32x4 a3 = __builtin_nontemporal_load(&in[baseA + 3 * PLANE4]);

        // --- position B: issue 4 loads (independent, in flight with A's) ---
        const bool hasB = (p2 < npos4);
        const int bB = p2 >> PLANE4_SHIFT;
        const long baseB = hasB ? (((long)(bB * NS) << PLANE4_SHIFT) + (p2 & (PLANE4 - 1)))
                                : baseA;
        const f32x4 b0 = __builtin_nontemporal_load(&in[baseB]);
        const f32x4 b1 = __builtin_nontemporal_load(&in[baseB + PLANE4]);
        const f32x4 b2 = __builtin_nontemporal_load(&in[baseB + 2 * PLANE4]);
        const f32x4 b3 = __builtin_nontemporal_load(&in[baseB + 3 * PLANE4]);

#pragma unroll
        for (int o = 0; o < NS; ++o) {
            f32x4 r = m[o*4+0]*a0 + m[o*4+1]*a1 + m[o*4+2]*a2 + m[o*4+3]*a3;
            __builtin_nontemporal_store(r, &out[baseA + (long)o * PLANE4]);
        }

        if (hasB) {
#pragma unroll
            for (int o = 0; o < NS; ++o) {
                f32x4 r = m[o*4+0]*b0 + m[o*4+1]*b1 + m[o*4+2]*b2 + m[o*4+3]*b3;
                __builtin_nontemporal_store(r, &out[baseB + (long)o * PLANE4]);
            }
        }
    }
}

extern "C" void kernel_launch(void* const* d_in, const int* in_sizes, int n_in,
                              void* d_out, int out_size, void* d_ws, size_t ws_size,
                              hipStream_t stream) {
    const float* residuals   = (const float*)d_in[0];  // (B*S, T, D) = (8,4096,2048) f32
    const float* Hres_logits = (const float*)d_in[1];  // (4,4)
    const float* Hpre_logits = (const float*)d_in[2];  // (4,)
    const float* Hpost_logits= (const float*)d_in[3];  // (4,)
    float* out = (float*)d_out;
    float* M   = (float*)d_ws;                         // 16 floats

    hc_coef_kernel<<<1, 64, 0, stream>>>(Hres_logits, Hpre_logits, Hpost_logits, M);

    const int npos4 = out_size / (NS * 4);             // B*T*D/4 = 4194304
    // 4096 blocks x 256 threads: each thread handles exactly 4 positions
    // (2 loop iterations x unroll-2).
    hc_mix_kernel<<<4096, 256, 0, stream>>>(
        (const f32x4*)residuals, M, (f32x4*)out, npos4);
}

// Round 4
// 117.654 us; speedup vs baseline: 1.2300x; 1.0932x over previous
//
#include <hip/hip_runtime.h>
#include <math.h>

#define NS 4
#define SINKHORN_ITERS 10
#define TAU 0.05f

// T*D/4 in float4 units: 4096*2048/4 = 2^21
#define PLANE4 2097152L
#define PLANE4_SHIFT 21
#define NTHREADS (1 << 20)   // 4096 blocks x 256 threads

typedef float f32x4 __attribute__((ext_vector_type(4)));

// ---------------------------------------------------------------------------
// Kernel 1: compute M[4][4] = H_res^T + H_post (outer) H_pre  into d_ws.
// ---------------------------------------------------------------------------
__global__ void hc_coef_kernel(const float* __restrict__ Hres_logits,
                               const float* __restrict__ Hpre_logits,
                               const float* __restrict__ Hpost_logits,
                               float* __restrict__ M) {
    if (threadIdx.x != 0 || blockIdx.x != 0) return;

    float Z[NS][NS], u[NS], v[NS];
    for (int i = 0; i < NS; ++i)
        for (int j = 0; j < NS; ++j)
            Z[i][j] = Hres_logits[i * NS + j] / TAU;

    const float logm = -logf((float)NS);
    for (int i = 0; i < NS; ++i) { u[i] = 0.f; v[i] = 0.f; }

    for (int it = 0; it < SINKHORN_ITERS; ++it) {
        for (int i = 0; i < NS; ++i) {
            float mx = -INFINITY;
            for (int j = 0; j < NS; ++j) mx = fmaxf(mx, Z[i][j] + v[j]);
            float s = 0.f;
            for (int j = 0; j < NS; ++j) s += expf(Z[i][j] + v[j] - mx);
            u[i] = logm - (mx + logf(s));
        }
        for (int j = 0; j < NS; ++j) {
            float mx = -INFINITY;
            for (int i = 0; i < NS; ++i) mx = fmaxf(mx, Z[i][j] + u[i]);
            float s = 0.f;
            for (int i = 0; i < NS; ++i) s += expf(Z[i][j] + u[i] - mx);
            v[j] = logm - (mx + logf(s));
        }
    }

    float Hres[NS][NS];
    for (int i = 0; i < NS; ++i)
        for (int j = 0; j < NS; ++j)
            Hres[i][j] = expf(Z[i][j] + u[i] + v[j]) * (float)NS;

    float hp[NS], mx = -INFINITY, s = 0.f;
    for (int i = 0; i < NS; ++i) mx = fmaxf(mx, Hpre_logits[i]);
    for (int i = 0; i < NS; ++i) { hp[i] = expf(Hpre_logits[i] - mx); s += hp[i]; }
    for (int i = 0; i < NS; ++i) hp[i] /= s;

    float ho[NS];
    mx = -INFINITY; s = 0.f;
    for (int i = 0; i < NS; ++i) mx = fmaxf(mx, Hpost_logits[i]);
    for (int i = 0; i < NS; ++i) { ho[i] = expf(Hpost_logits[i] - mx); s += ho[i]; }
    for (int i = 0; i < NS; ++i) ho[i] /= s;

    for (int so = 0; so < NS; ++so)
        for (int si = 0; si < NS; ++si)
            M[so * NS + si] = Hres[si][so] + ho[so] * hp[si];
}

// ---------------------------------------------------------------------------
// Kernel 2 (fast path): flat unroll-4, exactly 2^20 threads, each owns
// positions  gtid + k*2^20, k=0..3.  Since 2^20 = PLANE4/2:
//   b = k>>1 (compile-time), q = gtid + (k&1)*2^20 (const offset).
// 16 NT loads issued back-to-back, then 16 plain stores. No loop, no branch.
// ---------------------------------------------------------------------------
__global__ __launch_bounds__(256) void hc_mix_flat(
        const f32x4* __restrict__ in,
        const float* __restrict__ Mg,
        f32x4* __restrict__ out) {
    float m[16];
#pragma unroll
    for (int k = 0; k < 16; ++k) m[k] = Mg[k];

    const long gtid = blockIdx.x * blockDim.x + threadIdx.x;

    f32x4 v[4][NS];
#pragma unroll
    for (int k = 0; k < 4; ++k) {
        const long base = (long)(k >> 1) * (NS * PLANE4) + ((long)(k & 1) << 20) + gtid;
#pragma unroll
        for (int s = 0; s < NS; ++s)
            v[k][s] = __builtin_nontemporal_load(&in[base + (long)s * PLANE4]);
    }

#pragma unroll
    for (int k = 0; k < 4; ++k) {
        const long base = (long)(k >> 1) * (NS * PLANE4) + ((long)(k & 1) << 20) + gtid;
#pragma unroll
        for (int o = 0; o < NS; ++o) {
            out[base + (long)o * PLANE4] =
                m[o*4+0] * v[k][0] + m[o*4+1] * v[k][1] +
                m[o*4+2] * v[k][2] + m[o*4+3] * v[k][3];
        }
    }
}

// Generic fallback (any size), same math.
__global__ __launch_bounds__(256) void hc_mix_generic(
        const f32x4* __restrict__ in,
        const float* __restrict__ Mg,
        f32x4* __restrict__ out,
        int npos4) {
    float m[16];
#pragma unroll
    for (int k = 0; k < 16; ++k) m[k] = Mg[k];

    const int stride = gridDim.x * blockDim.x;
    for (int p = blockIdx.x * blockDim.x + threadIdx.x; p < npos4; p += stride) {
        const int b = p >> PLANE4_SHIFT;
        const long base = ((long)(b * NS) << PLANE4_SHIFT) + (p & (PLANE4 - 1));
        const f32x4 v0 = in[base];
        const f32x4 v1 = in[base + PLANE4];
        const f32x4 v2 = in[base + 2 * PLANE4];
        const f32x4 v3 = in[base + 3 * PLANE4];
#pragma unroll
        for (int o = 0; o < NS; ++o)
            out[base + (long)o * PLANE4] =
                m[o*4+0]*v0 + m[o*4+1]*v1 + m[o*4+2]*v2 + m[o*4+3]*v3;
    }
}

extern "C" void kernel_launch(void* const* d_in, const int* in_sizes, int n_in,
                              void* d_out, int out_size, void* d_ws, size_t ws_size,
                              hipStream_t stream) {
    const float* residuals   = (const float*)d_in[0];  // (B*S, T, D) = (8,4096,2048) f32
    const float* Hres_logits = (const float*)d_in[1];  // (4,4)
    const float* Hpre_logits = (const float*)d_in[2];  // (4,)
    const float* Hpost_logits= (const float*)d_in[3];  // (4,)
    float* out = (float*)d_out;
    float* M   = (float*)d_ws;                         // 16 floats

    hc_coef_kernel<<<1, 64, 0, stream>>>(Hres_logits, Hpre_logits, Hpost_logits, M);

    const int npos4 = out_size / (NS * 4);             // B*T*D/4 = 4194304
    if (npos4 == 4 * NTHREADS) {
        hc_mix_flat<<<NTHREADS / 256, 256, 0, stream>>>(
            (const f32x4*)residuals, M, (f32x4*)out);
    } else {
        hc_mix_generic<<<2048, 256, 0, stream>>>(
            (const f32x4*)residuals, M, (f32x4*)out, npos4);
    }
}